// Round 2
// baseline (200.346 us; speedup 1.0000x reference)
//
#include <hip/hip_runtime.h>

#define DD 256
#define BB 8
#define NA 360
#define CH 8            // h-chunks per angle
#define HC (DD / CH)    // 32 h-steps per chunk
#define TS 32           // pack tile

// ---------------- pack: (B,1,D,D) -> batch-innermost pN / transposed pT ----
// pN[(y*D+x)*B + b], pT[(x*D+y)*B + b]. 32x32 tile via LDS so BOTH outputs
// get coalesced float4 stores (round-1 pT scatter cost ~40us).
__global__ __launch_bounds__(256) void pack_tiled(const float* __restrict__ x,
                                                  float* __restrict__ pN,
                                                  float* __restrict__ pT) {
    __shared__ float t[BB][TS][TS + 1];           // 33.8 KB, pad kills conflicts
    const int tx = threadIdx.x & 31;
    const int ty = threadIdx.x >> 5;              // 0..7
    const int x0 = (blockIdx.x & 7) * TS;
    const int y0 = (blockIdx.x >> 3) * TS;

#pragma unroll
    for (int b = 0; b < BB; ++b)
#pragma unroll
        for (int r = ty; r < TS; r += 8)
            t[b][r][tx] = x[b * DD * DD + (y0 + r) * DD + x0 + tx];
    __syncthreads();

#pragma unroll
    for (int r = ty; r < TS; r += 8) {
        // pN: pixel (y0+r, x0+tx)
        float4 lo, hi;
        lo.x = t[0][r][tx]; lo.y = t[1][r][tx]; lo.z = t[2][r][tx]; lo.w = t[3][r][tx];
        hi.x = t[4][r][tx]; hi.y = t[5][r][tx]; hi.z = t[6][r][tx]; hi.w = t[7][r][tx];
        float4* p = (float4*)(pN + (size_t)((y0 + r) * DD + x0 + tx) * BB);
        p[0] = lo; p[1] = hi;
        // pT: linear pixel (x0+r)*D + (y0+tx) holds img[y0+tx][x0+r] = t[b][tx][r]
        float4 lo2, hi2;
        lo2.x = t[0][tx][r]; lo2.y = t[1][tx][r]; lo2.z = t[2][tx][r]; lo2.w = t[3][tx][r];
        hi2.x = t[4][tx][r]; hi2.y = t[5][tx][r]; hi2.z = t[6][tx][r]; hi2.w = t[7][tx][r];
        float4* q = (float4*)(pT + (size_t)((x0 + r) * DD + y0 + tx) * BB);
        q[0] = lo2; q[1] = hi2;
    }
}

// ---------------- radon gather ---------------------------------------------
// Wave = 32 w-positions x 2 batch-halves: each corner is ONE 16B load that,
// across the wave, consumes the full 32B/pixel of 32 pixels -> no duplicate
// cache-line touches (round-1 lo/hi pairs re-touched the same lines).
__global__ __launch_bounds__(256) void radon_kernel(const float* __restrict__ pN,
                                                    const float* __restrict__ pT,
                                                    float* __restrict__ out) {
    const int a    = blockIdx.x;            // angle
    const int hc   = blockIdx.y >> 1;       // h-chunk (0..CH-1)
    const int wseg = blockIdx.y & 1;        // w segment (0..1)
    const int tid  = threadIdx.x;
    const int wave = tid >> 6;              // 0..3
    const int lane = tid & 63;
    const int half = lane >> 5;             // 0: b0-3, 1: b4-7
    const int wl   = lane & 31;
    const int w    = wseg * 128 + wave * 32 + wl;

    const float ang = (float)a * 0.5f;
    const float t = ang * 0.017453292519943295f;
    const float s = sinf(t);
    const float c = cosf(t);

    const float uw  = (float)w - 127.5f;
    const float axN = fmaf(c, uw, 127.5f);  // ix at uh=0 term
    const float ayN = fmaf(s, uw, 127.5f);  // iy at uh=0 term

    // inner coord = memory-contiguous dim of chosen layout
    const float* __restrict__ P;
    float ax, dx, ay, dy;                   // inner = ax+dx*uh, outer = ay+dy*uh
    if (fabsf(s) <= fabsf(c)) { P = pN; ax = axN; dx = -s; ay = ayN; dy = c;  }
    else                      { P = pT; ax = ayN; dx = c;  ay = axN; dy = -s; }

    float acc[4] = {0.f, 0.f, 0.f, 0.f};
    const int h0 = hc * HC;

#pragma unroll 2
    for (int i = 0; i < HC; ++i) {
        const float uh = (float)(h0 + i) - 127.5f;
        const float ix = fmaf(dx, uh, ax);          // inner
        const float iy = fmaf(dy, uh, ay);          // outer (row)
        const float x0f = floorf(ix), y0f = floorf(iy);
        const float wx1 = ix - x0f, wy1 = iy - y0f;
        const float wx0 = 1.f - wx1, wy0 = 1.f - wy1;
        const int x0 = (int)x0f, y0 = (int)y0f;
        const float vx0 = ((unsigned)x0 < 256u) ? wx0 : 0.f;
        const float vx1 = ((unsigned)(x0 + 1) < 256u) ? wx1 : 0.f;
        const float vy0 = ((unsigned)y0 < 256u) ? wy0 : 0.f;
        const float vy1 = ((unsigned)(y0 + 1) < 256u) ? wy1 : 0.f;
        const int x0c = min(max(x0, 0), 255);
        const int x1c = min(max(x0 + 1, 0), 255);
        const int y0c = min(max(y0, 0), 255);
        const int y1c = min(max(y0 + 1, 0), 255);
        const float w00 = vx0 * vy0, w10 = vx1 * vy0;
        const float w01 = vx0 * vy1, w11 = vx1 * vy1;

        const int hb = half * 4;
        const float4 q00 = *(const float4*)(P + (size_t)(y0c * DD + x0c) * BB + hb);
        const float4 q10 = *(const float4*)(P + (size_t)(y0c * DD + x1c) * BB + hb);
        const float4 q01 = *(const float4*)(P + (size_t)(y1c * DD + x0c) * BB + hb);
        const float4 q11 = *(const float4*)(P + (size_t)(y1c * DD + x1c) * BB + hb);

        acc[0] = fmaf(q00.x, w00, acc[0]); acc[1] = fmaf(q00.y, w00, acc[1]);
        acc[2] = fmaf(q00.z, w00, acc[2]); acc[3] = fmaf(q00.w, w00, acc[3]);
        acc[0] = fmaf(q10.x, w10, acc[0]); acc[1] = fmaf(q10.y, w10, acc[1]);
        acc[2] = fmaf(q10.z, w10, acc[2]); acc[3] = fmaf(q10.w, w10, acc[3]);
        acc[0] = fmaf(q01.x, w01, acc[0]); acc[1] = fmaf(q01.y, w01, acc[1]);
        acc[2] = fmaf(q01.z, w01, acc[2]); acc[3] = fmaf(q01.w, w01, acc[3]);
        acc[0] = fmaf(q11.x, w11, acc[0]); acc[1] = fmaf(q11.y, w11, acc[1]);
        acc[2] = fmaf(q11.z, w11, acc[2]); acc[3] = fmaf(q11.w, w11, acc[3]);
    }

    const float sc = 1.0f / 256.0f;
#pragma unroll
    for (int j = 0; j < 4; ++j) {
        float* o = out + (size_t)(half * 4 + j) * NA * DD + (size_t)a * DD + w;
        atomicAdd(o, acc[j] * sc);
    }
}

// ---------------- fallback (ws too small): direct gather -------------------
__global__ __launch_bounds__(256) void radon_direct(const float* __restrict__ x,
                                                    float* __restrict__ out) {
    const int a  = blockIdx.x;
    const int hc = blockIdx.y;
    const int w  = threadIdx.x;
    const float ang = (float)a * 0.5f;
    const float t = ang * 0.017453292519943295f;
    const float s = sinf(t);
    const float c = cosf(t);
    const float uw = (float)w - 127.5f;
    const float ax = fmaf(c, uw, 127.5f);
    const float ay = fmaf(s, uw, 127.5f);

    float acc[BB];
#pragma unroll
    for (int b = 0; b < BB; ++b) acc[b] = 0.f;

    const int h0 = hc * HC;
    for (int i = 0; i < HC; ++i) {
        const float uh = (float)(h0 + i) - 127.5f;
        const float ix = fmaf(-s, uh, ax);
        const float iy = fmaf(c, uh, ay);
        const float x0f = floorf(ix), y0f = floorf(iy);
        const float wx1 = ix - x0f, wy1 = iy - y0f;
        const float wx0 = 1.f - wx1, wy0 = 1.f - wy1;
        const int x0 = (int)x0f, y0 = (int)y0f;
        const float vx0 = ((unsigned)x0 < 256u) ? wx0 : 0.f;
        const float vx1 = ((unsigned)(x0 + 1) < 256u) ? wx1 : 0.f;
        const float vy0 = ((unsigned)y0 < 256u) ? wy0 : 0.f;
        const float vy1 = ((unsigned)(y0 + 1) < 256u) ? wy1 : 0.f;
        const int x0c = min(max(x0, 0), 255);
        const int x1c = min(max(x0 + 1, 0), 255);
        const int y0c = min(max(y0, 0), 255);
        const int y1c = min(max(y0 + 1, 0), 255);
        const float w00 = vx0 * vy0, w10 = vx1 * vy0;
        const float w01 = vx0 * vy1, w11 = vx1 * vy1;
        const int l00 = y0c * DD + x0c, l10 = y0c * DD + x1c;
        const int l01 = y1c * DD + x0c, l11 = y1c * DD + x1c;
#pragma unroll
        for (int b = 0; b < BB; ++b) {
            const float* ib = x + (size_t)b * DD * DD;
            acc[b] = fmaf(ib[l00], w00, acc[b]);
            acc[b] = fmaf(ib[l10], w10, acc[b]);
            acc[b] = fmaf(ib[l01], w01, acc[b]);
            acc[b] = fmaf(ib[l11], w11, acc[b]);
        }
    }

    const float sc = 1.0f / 256.0f;
    float* o = out + (size_t)a * DD + w;
#pragma unroll
    for (int b = 0; b < BB; ++b)
        atomicAdd(o + (size_t)b * NA * DD, acc[b] * sc);
}

extern "C" void kernel_launch(void* const* d_in, const int* in_sizes, int n_in,
                              void* d_out, int out_size, void* d_ws, size_t ws_size,
                              hipStream_t stream) {
    const float* x = (const float*)d_in[0];
    float* out = (float*)d_out;

    // atomic accumulation -> zero the poisoned output first
    hipMemsetAsync(d_out, 0, (size_t)out_size * sizeof(float), stream);

    const size_t need = 2ull * DD * DD * BB * sizeof(float);  // 4 MiB
    if (ws_size >= need) {
        float* pN = (float*)d_ws;
        float* pT = pN + (size_t)DD * DD * BB;
        pack_tiled<<<64, 256, 0, stream>>>(x, pN, pT);
        radon_kernel<<<dim3(NA, CH * 2), 256, 0, stream>>>(pN, pT, out);
    } else {
        radon_direct<<<dim3(NA, DD / HC), 256, 0, stream>>>(x, out);
    }
}

// Round 3
// 145.449 us; speedup vs baseline: 1.3774x; 1.3774x over previous
//
#include <hip/hip_runtime.h>

#define DD 256
#define BB 8
#define NA 360
#define CH 8            // h-chunks per angle
#define HC (DD / CH)    // 32 h-steps per chunk
#define TS 32           // pack tile

// ---- bf16 helpers ---------------------------------------------------------
__device__ __forceinline__ unsigned bf16_rne(float f) {
    unsigned u = __float_as_uint(f);
    return (u + 0x7fffu + ((u >> 16) & 1u)) >> 16;
}
__device__ __forceinline__ unsigned pack2(float a, float b) {
    return bf16_rne(a) | (bf16_rne(b) << 16);
}
// one uint4 = 8 bf16 = all 8 batches of one pixel; dword j = batches 2j, 2j+1
__device__ __forceinline__ void ufma(uint4 q, float wgt, float* acc) {
    acc[0] = fmaf(__uint_as_float(q.x << 16),          wgt, acc[0]);
    acc[1] = fmaf(__uint_as_float(q.x & 0xffff0000u),  wgt, acc[1]);
    acc[2] = fmaf(__uint_as_float(q.y << 16),          wgt, acc[2]);
    acc[3] = fmaf(__uint_as_float(q.y & 0xffff0000u),  wgt, acc[3]);
    acc[4] = fmaf(__uint_as_float(q.z << 16),          wgt, acc[4]);
    acc[5] = fmaf(__uint_as_float(q.z & 0xffff0000u),  wgt, acc[5]);
    acc[6] = fmaf(__uint_as_float(q.w << 16),          wgt, acc[6]);
    acc[7] = fmaf(__uint_as_float(q.w & 0xffff0000u),  wgt, acc[7]);
}

// ---- pack: (B,1,D,D) fp32 -> bf16x8-per-pixel pN (row-major) + pT (transposed)
__global__ __launch_bounds__(256) void pack_bf16(const float* __restrict__ x,
                                                 uint4* __restrict__ pN,
                                                 uint4* __restrict__ pT) {
    __shared__ uint4 t[TS][TS + 1];               // ~16.9 KB
    const int tx = threadIdx.x & 31;
    const int ty = threadIdx.x >> 5;              // 0..7
    const int x0 = (blockIdx.x & 7) * TS;
    const int y0 = (blockIdx.x >> 3) * TS;

#pragma unroll
    for (int r = ty; r < TS; r += 8) {
        const int pix = (y0 + r) * DD + x0 + tx;
        uint4 v;
        v.x = pack2(x[0 * DD * DD + pix], x[1 * DD * DD + pix]);
        v.y = pack2(x[2 * DD * DD + pix], x[3 * DD * DD + pix]);
        v.z = pack2(x[4 * DD * DD + pix], x[5 * DD * DD + pix]);
        v.w = pack2(x[6 * DD * DD + pix], x[7 * DD * DD + pix]);
        pN[pix] = v;                               // coalesced
        t[r][tx] = v;
    }
    __syncthreads();
#pragma unroll
    for (int r = ty; r < TS; r += 8)               // pT[(xx*D+yy)] = img[yy][xx]
        pT[(x0 + r) * DD + y0 + tx] = t[tx][r];    // coalesced store
}

// ---- radon gather: 1 b128 load per corner (all 8 batches) -----------------
__global__ __launch_bounds__(256) void radon_bf16(const uint4* __restrict__ pN,
                                                  const uint4* __restrict__ pT,
                                                  float* __restrict__ out) {
    const int a  = blockIdx.x;   // angle
    const int hc = blockIdx.y;   // h-chunk
    const int w  = threadIdx.x;  // output column (0..255)

    const float ang = (float)a * 0.5f;
    const float t = ang * 0.017453292519943295f;
    const float s = sinf(t);
    const float c = cosf(t);

    const float uw  = (float)w - 127.5f;
    const float axN = fmaf(c, uw, 127.5f);
    const float ayN = fmaf(s, uw, 127.5f);

    // inner coord = contiguous dim of chosen layout (spread = min(|s|,|c|) per h)
    const uint4* __restrict__ P;
    float ax, dx, ay, dy;                    // inner = ax+dx*uh, outer = ay+dy*uh
    if (fabsf(s) <= fabsf(c)) { P = pN; ax = axN; dx = -s; ay = ayN; dy = c;  }
    else                      { P = pT; ax = ayN; dx = c;  ay = axN; dy = -s; }

    float acc[BB];
#pragma unroll
    for (int b = 0; b < BB; ++b) acc[b] = 0.f;

    const int h0 = hc * HC;
#pragma unroll 2
    for (int i = 0; i < HC; ++i) {
        const float uh = (float)(h0 + i) - 127.5f;
        const float ix = fmaf(dx, uh, ax);           // inner
        const float iy = fmaf(dy, uh, ay);           // outer (row)
        const float x0f = floorf(ix), y0f = floorf(iy);
        const float wx1 = ix - x0f, wy1 = iy - y0f;
        const float wx0 = 1.f - wx1, wy0 = 1.f - wy1;
        const int x0 = (int)x0f, y0 = (int)y0f;
        const float vx0 = ((unsigned)x0 < 256u) ? wx0 : 0.f;
        const float vx1 = ((unsigned)(x0 + 1) < 256u) ? wx1 : 0.f;
        const float vy0 = ((unsigned)y0 < 256u) ? wy0 : 0.f;
        const float vy1 = ((unsigned)(y0 + 1) < 256u) ? wy1 : 0.f;
        const int x0c = min(max(x0, 0), 255);
        const int x1c = min(max(x0 + 1, 0), 255);
        const int y0c = min(max(y0, 0), 255);
        const int y1c = min(max(y0 + 1, 0), 255);
        const float w00 = vx0 * vy0, w10 = vx1 * vy0;
        const float w01 = vx0 * vy1, w11 = vx1 * vy1;

        const uint4 q00 = P[y0c * DD + x0c];
        const uint4 q10 = P[y0c * DD + x1c];
        const uint4 q01 = P[y1c * DD + x0c];
        const uint4 q11 = P[y1c * DD + x1c];

        ufma(q00, w00, acc);
        ufma(q10, w10, acc);
        ufma(q01, w01, acc);
        ufma(q11, w11, acc);
    }

    const float sc = 1.0f / 256.0f;
#pragma unroll
    for (int b = 0; b < BB; ++b)
        atomicAdd(out + (size_t)b * NA * DD + (size_t)a * DD + w, acc[b] * sc);
}

// ---- fallback (ws too small): direct fp32 gather --------------------------
__global__ __launch_bounds__(256) void radon_direct(const float* __restrict__ x,
                                                    float* __restrict__ out) {
    const int a  = blockIdx.x;
    const int hc = blockIdx.y;
    const int w  = threadIdx.x;
    const float ang = (float)a * 0.5f;
    const float t = ang * 0.017453292519943295f;
    const float s = sinf(t);
    const float c = cosf(t);
    const float uw = (float)w - 127.5f;
    const float ax = fmaf(c, uw, 127.5f);
    const float ay = fmaf(s, uw, 127.5f);

    float acc[BB];
#pragma unroll
    for (int b = 0; b < BB; ++b) acc[b] = 0.f;

    const int h0 = hc * HC;
    for (int i = 0; i < HC; ++i) {
        const float uh = (float)(h0 + i) - 127.5f;
        const float ix = fmaf(-s, uh, ax);
        const float iy = fmaf(c, uh, ay);
        const float x0f = floorf(ix), y0f = floorf(iy);
        const float wx1 = ix - x0f, wy1 = iy - y0f;
        const float wx0 = 1.f - wx1, wy0 = 1.f - wy1;
        const int x0 = (int)x0f, y0 = (int)y0f;
        const float vx0 = ((unsigned)x0 < 256u) ? wx0 : 0.f;
        const float vx1 = ((unsigned)(x0 + 1) < 256u) ? wx1 : 0.f;
        const float vy0 = ((unsigned)y0 < 256u) ? wy0 : 0.f;
        const float vy1 = ((unsigned)(y0 + 1) < 256u) ? wy1 : 0.f;
        const int x0c = min(max(x0, 0), 255);
        const int x1c = min(max(x0 + 1, 0), 255);
        const int y0c = min(max(y0, 0), 255);
        const int y1c = min(max(y0 + 1, 0), 255);
        const float w00 = vx0 * vy0, w10 = vx1 * vy0;
        const float w01 = vx0 * vy1, w11 = vx1 * vy1;
        const int l00 = y0c * DD + x0c, l10 = y0c * DD + x1c;
        const int l01 = y1c * DD + x0c, l11 = y1c * DD + x1c;
#pragma unroll
        for (int b = 0; b < BB; ++b) {
            const float* ib = x + (size_t)b * DD * DD;
            acc[b] = fmaf(ib[l00], w00, acc[b]);
            acc[b] = fmaf(ib[l10], w10, acc[b]);
            acc[b] = fmaf(ib[l01], w01, acc[b]);
            acc[b] = fmaf(ib[l11], w11, acc[b]);
        }
    }

    const float sc = 1.0f / 256.0f;
    float* o = out + (size_t)a * DD + w;
#pragma unroll
    for (int b = 0; b < BB; ++b)
        atomicAdd(o + (size_t)b * NA * DD, acc[b] * sc);
}

extern "C" void kernel_launch(void* const* d_in, const int* in_sizes, int n_in,
                              void* d_out, int out_size, void* d_ws, size_t ws_size,
                              hipStream_t stream) {
    const float* x = (const float*)d_in[0];
    float* out = (float*)d_out;

    // atomic accumulation -> zero the poisoned output first
    hipMemsetAsync(d_out, 0, (size_t)out_size * sizeof(float), stream);

    const size_t need = 2ull * DD * DD * sizeof(uint4);  // 2 MiB
    if (ws_size >= need) {
        uint4* pN = (uint4*)d_ws;
        uint4* pT = pN + (size_t)DD * DD;
        pack_bf16<<<64, 256, 0, stream>>>(x, pN, pT);
        radon_bf16<<<dim3(NA, CH), 256, 0, stream>>>(pN, pT, out);
    } else {
        radon_direct<<<dim3(NA, CH), 256, 0, stream>>>(x, out);
    }
}